// Round 10
// baseline (433.863 us; speedup 1.0000x reference)
//
#include <hip/hip_runtime.h>
#include <hip/hip_fp16.h>

#define SQH 0.70710678118654752440f
#define NC 64

typedef float nfloat4 __attribute__((ext_vector_type(4)));

// Half-sample symmetric reflection, L a compile-time power of two.
template<int L>
static __device__ __forceinline__ int refl(int i) {
    int j = i & (2 * L - 1);
    return (j >= L) ? (2 * L - 1 - j) : j;
}

// c2q on a float4 = two adjacent complex pairs (cols 2jj..2jj+3).
// p0 = values at even row (2ii), p1 = values at odd row (2ii+1).
static __device__ __forceinline__ void c2q_quad4(float4 A, float4 B,
                                                 float4& p0, float4& p1) {
    p0 = make_float4(SQH * (A.x + B.x), SQH * (A.y + B.y),
                     SQH * (A.z + B.z), SQH * (A.w + B.w));
    p1 = make_float4(SQH * (A.y - B.y), SQH * (B.x - A.x),
                     SQH * (A.w - B.w), SQH * (B.z - A.z));
}

static __device__ __forceinline__ void fma4(float4& a, float s, float4 v) {
    a.x += s * v.x; a.y += s * v.y; a.z += s * v.z; a.w += s * v.w;
}

// 4-element group load/store, fp32 or fp16 backing.
static __device__ __forceinline__ float4 ld4(const float* p, size_t i4) {
    return ((const float4*)p)[i4];
}
static __device__ __forceinline__ float4 ld4(const __half* p, size_t i4) {
    const __half2* h = (const __half2*)p;
    float2 lo = __half22float2(h[2 * i4]);
    float2 hi = __half22float2(h[2 * i4 + 1]);
    return make_float4(lo.x, lo.y, hi.x, hi.y);
}
static __device__ __forceinline__ void st4(float* p, size_t i4, float4 v) {
    ((float4*)p)[i4] = v;
}
static __device__ __forceinline__ void st4(__half* p, size_t i4, float4 v) {
    __half2* h = (__half2*)p;
    h[2 * i4]     = __float22half2_rn(make_float2(v.x, v.y));
    h[2 * i4 + 1] = __float22half2_rn(make_float2(v.z, v.w));
}

static __device__ __forceinline__ __half2 h2swap(__half2 v) {
    __half2 r; r.x = v.y; r.y = v.x; return r;
}

// ---- Fused inverse level: colifilt (c2q fused) -> fp16 LDS(+refl halo) -> rowifilt.
// ll: (NC,R_,W_), yh: (NC,6,R_/2,W_/2,2) -> out: (NC,2R_,2W_).
// Stage-A task = 4 cols x 4 output rows. VGPR capped for 8 waves/SIMD.
template<int R_, int W_, int TY, typename InT, typename OutT>
__global__ __launch_bounds__(256, 8) void k_i(const InT* __restrict__ ll,
                                              const float* __restrict__ yh,
                                              OutT* __restrict__ out,
                                              const float* __restrict__ g0a, const float* __restrict__ g0b,
                                              const float* __restrict__ g1a, const float* __restrict__ g1b) {
    constexpr int RH = R_ / 2, WQ = W_ / 4, W2 = W_ / 2;
    constexpr int SLABS = 2 * R_ / TY;
    constexpr int SW2 = W2 + 5;            // [2 left-halo | W2 | 3 right-halo] half2
    __shared__ __half2 Y1h[TY][SW2], Y2h[TY][SW2];

    constexpr int NBLK = SLABS * NC;
    int bid = blockIdx.x;
    int idx = (bid & 7) * (NBLK >> 3) + (bid >> 3);
    int nc = idx / SLABS, slab = idx % SLABS;
    int nc6 = nc * 6;
    int R0 = slab * TY, i0 = R0 >> 2;
    bool edge = (slab == 0) || (slab == SLABS - 1);

    const InT* llp = ll + (size_t)nc * R_ * W_;
    const float4* yh4 = (const float4*)yh;
    const float4* pHLa = yh4 + (size_t)(nc6 + 2) * RH * WQ;
    const float4* pHLb = yh4 + (size_t)(nc6 + 3) * RH * WQ;
    const float4* pLHa = yh4 + (size_t)(nc6 + 0) * RH * WQ;
    const float4* pLHb = yh4 + (size_t)(nc6 + 5) * RH * WQ;
    const float4* pHHa = yh4 + (size_t)(nc6 + 1) * RH * WQ;
    const float4* pHHb = yh4 + (size_t)(nc6 + 4) * RH * WQ;

    // ---- Stage A: column inverse filter. Task = 4 cols x 4 output rows.
    constexpr int ATASK = WQ * (TY / 4);
    for (int task = threadIdx.x; task < ATASK; task += 256) {
        int jq = task & (WQ - 1);
        int gl = task / WQ;
        int i  = i0 + gl;

        float4 a10 = {0,0,0,0}, a20 = {0,0,0,0}, a11 = {0,0,0,0}, a21 = {0,0,0,0};
        float4 a12 = {0,0,0,0}, a22 = {0,0,0,0}, a13 = {0,0,0,0}, a23 = {0,0,0,0};
#pragma unroll
        for (int t = 0; t < 5; ++t) {
            float4 lE, lO, hlE, hlO, lhE, lhO, hhE, hhO;
            if (edge) {
                int rE = refl<R_>(2 * i - 4 + 2 * t);
                int rO = refl<R_>(2 * i - 3 + 2 * t);
                lE = ld4(llp, (size_t)rE * WQ + jq);
                lO = ld4(llp, (size_t)rO * WQ + jq);
                int diE = rE & 1;
                size_t off = (size_t)(rE >> 1) * WQ + jq;
                float4 p0, p1;
                c2q_quad4(pHLa[off], pHLb[off], p0, p1);
                hlE = diE ? p1 : p0;  hlO = diE ? p0 : p1;
                c2q_quad4(pLHa[off], pLHb[off], p0, p1);
                lhE = diE ? p1 : p0;  lhO = diE ? p0 : p1;
                c2q_quad4(pHHa[off], pHHb[off], p0, p1);
                hhE = diE ? p1 : p0;  hhO = diE ? p0 : p1;
            } else {
                lE = ld4(llp, (size_t)(2 * i - 4 + 2 * t) * WQ + jq);
                lO = ld4(llp, (size_t)(2 * i - 3 + 2 * t) * WQ + jq);
                size_t off = (size_t)(i - 2 + t) * WQ + jq;
                c2q_quad4(pHLa[off], pHLb[off], hlE, hlO);
                c2q_quad4(pLHa[off], pLHb[off], lhE, lhO);
                c2q_quad4(pHHa[off], pHHb[off], hhE, hhO);
            }
            float b0o = g0b[2 * t + 1], a0o = g0a[2 * t + 1];
            float b0e = g0b[2 * t],     a0e = g0a[2 * t];
            float b1o = g1b[2 * t + 1], a1o = g1a[2 * t + 1];
            float b1e = g1b[2 * t],     a1e = g1a[2 * t];
            fma4(a10, b0o, lE);  fma4(a10, b1o, lhO);
            fma4(a20, b0o, hlE); fma4(a20, b1o, hhO);
            fma4(a11, a0o, lO);  fma4(a11, a1o, lhE);
            fma4(a21, a0o, hlO); fma4(a21, a1o, hhE);
            fma4(a12, b0e, lE);  fma4(a12, b1e, lhO);
            fma4(a22, b0e, hlE); fma4(a22, b1e, hhO);
            fma4(a13, a0e, lO);  fma4(a13, a1e, lhE);
            fma4(a23, a0e, hlO); fma4(a23, a1e, hhE);
        }
        int rl = 4 * gl, xc2 = 2 * jq + 2;
        Y1h[rl + 0][xc2] = __float22half2_rn(make_float2(a10.x, a10.y));
        Y1h[rl + 0][xc2 + 1] = __float22half2_rn(make_float2(a10.z, a10.w));
        Y2h[rl + 0][xc2] = __float22half2_rn(make_float2(a20.x, a20.y));
        Y2h[rl + 0][xc2 + 1] = __float22half2_rn(make_float2(a20.z, a20.w));
        Y1h[rl + 1][xc2] = __float22half2_rn(make_float2(a11.x, a11.y));
        Y1h[rl + 1][xc2 + 1] = __float22half2_rn(make_float2(a11.z, a11.w));
        Y2h[rl + 1][xc2] = __float22half2_rn(make_float2(a21.x, a21.y));
        Y2h[rl + 1][xc2 + 1] = __float22half2_rn(make_float2(a21.z, a21.w));
        Y1h[rl + 2][xc2] = __float22half2_rn(make_float2(a12.x, a12.y));
        Y1h[rl + 2][xc2 + 1] = __float22half2_rn(make_float2(a12.z, a12.w));
        Y2h[rl + 2][xc2] = __float22half2_rn(make_float2(a22.x, a22.y));
        Y2h[rl + 2][xc2 + 1] = __float22half2_rn(make_float2(a22.z, a22.w));
        Y1h[rl + 3][xc2] = __float22half2_rn(make_float2(a13.x, a13.y));
        Y1h[rl + 3][xc2 + 1] = __float22half2_rn(make_float2(a13.z, a13.w));
        Y2h[rl + 3][xc2] = __float22half2_rn(make_float2(a23.x, a23.y));
        Y2h[rl + 3][xc2 + 1] = __float22half2_rn(make_float2(a23.z, a23.w));
    }
    __syncthreads();

    // ---- Halo fill: pre-reflected, pair-swapped mirrors.
    for (int t = threadIdx.x; t < TY * 5; t += 256) {
        int r = t / 5, h = t % 5;
        int dst, src;
        if (h < 2) { dst = h;              src = 3 - h; }
        else       { int k = h - 2; dst = W2 + 2 + k; src = W2 + 1 - k; }
        Y1h[r][dst] = h2swap(Y1h[r][src]);
        Y2h[r][dst] = h2swap(Y2h[r][src]);
    }
    __syncthreads();

    // ---- Stage B: row inverse filter from fp16 LDS (dense half2 reads).
    constexpr int QW = W_ / 2;   // quads per output row (2W_/4)
    for (int task = threadIdx.x; task < TY * QW; task += 256) {
        int j = task & (QW - 1);
        int r = task / QW;
        float2 v1[5], v2[5];     // .x = even series, .y = odd series
#pragma unroll
        for (int t = 0; t < 5; ++t) {
            v1[t] = __half22float2(Y1h[r][j + t]);
            v2[t] = __half22float2(Y2h[r][j + t]);
        }
        float4 o = make_float4(0.f, 0.f, 0.f, 0.f);
#pragma unroll
        for (int t = 0; t < 5; ++t) {
            float b0o = g0b[2 * t + 1], a0o = g0a[2 * t + 1];
            float b0e = g0b[2 * t],     a0e = g0a[2 * t];
            float b1o = g1b[2 * t + 1], a1o = g1a[2 * t + 1];
            float b1e = g1b[2 * t],     a1e = g1a[2 * t];
            o.x += b0o * v1[t].x + b1o * v2[t].y;
            o.y += a0o * v1[t].y + a1o * v2[t].x;
            o.z += b0e * v1[t].x + b1e * v2[t].y;
            o.w += a0e * v1[t].y + a1e * v2[t].x;
        }
        st4(out, (size_t)(nc * 2 * R_ + R0 + r) * QW + j, o);
    }
}

// ---- Fused final level: colfilter(7/5-tap, c2q fused) -> fp16 LDS -> rowfilter.
// Stage-A task = 4 cols x 4 output rows (one gg).
template<int H, int W, int TY, typename InT>
__global__ __launch_bounds__(256, 8) void k_f0(const InT* __restrict__ ll,
                                               const float* __restrict__ yh,
                                               float* __restrict__ out,
                                               const float* __restrict__ g0o,
                                               const float* __restrict__ g1o) {
    constexpr int RH = H / 2, WQ = W / 4, W2 = W / 2;
    constexpr int SLABS = H / TY;
    constexpr int SW2 = W2 + 5;
    __shared__ __half2 Y1h[TY][SW2], Y2h[TY][SW2];

    constexpr int NBLK = SLABS * NC;
    int bid = blockIdx.x;
    int idx = (bid & 7) * (NBLK >> 3) + (bid >> 3);
    int nc = idx / SLABS, slab = idx % SLABS;
    int nc6 = nc * 6;
    int r0 = slab * TY;
    bool edge = (slab == 0) || (slab == SLABS - 1);

    const InT* llp = ll + (size_t)nc * H * W;
    const float4* yh4 = (const float4*)yh;
    const float4* pHLa = yh4 + (size_t)(nc6 + 2) * RH * WQ;
    const float4* pHLb = yh4 + (size_t)(nc6 + 3) * RH * WQ;
    const float4* pLHa = yh4 + (size_t)(nc6 + 0) * RH * WQ;
    const float4* pLHb = yh4 + (size_t)(nc6 + 5) * RH * WQ;
    const float4* pHHa = yh4 + (size_t)(nc6 + 1) * RH * WQ;
    const float4* pHHb = yh4 + (size_t)(nc6 + 4) * RH * WQ;

    float f0[7], f1[5];
#pragma unroll
    for (int k = 0; k < 7; ++k) f0[k] = g0o[k];
#pragma unroll
    for (int k = 0; k < 5; ++k) f1[k] = g1o[k];

    // ---- Stage A: column filter. Task = 4 cols x 4 output rows.
    constexpr int ATASK = WQ * (TY / 4);
    for (int task = threadIdx.x; task < ATASK; task += 256) {
        int jq = task & (WQ - 1);
        int gl = task / WQ;
        int gg = (r0 >> 2) + gl;

        float4 a1[4], a2[4];
#pragma unroll
        for (int q = 0; q < 4; ++q) { a1[q] = make_float4(0,0,0,0); a2[q] = make_float4(0,0,0,0); }

        // Lowpass path from ll: window rows 4gg-3+m, m=0..9, 7-tap f0.
#pragma unroll
        for (int m = 0; m < 10; ++m) {
            float4 v;
            if (edge) v = ld4(llp, (size_t)refl<H>(4 * gg - 3 + m) * WQ + jq);
            else      v = ld4(llp, (size_t)(4 * gg - 3 + m) * WQ + jq);
#pragma unroll
            for (int q = 0; q < 4; ++q)
                if (m - q >= 0 && m - q < 7) fma4(a1[q], f0[m - q], v);
        }
        // HL band (7-tap f0 into a2): pairs pp cover window m = 2pp-1 (E), 2pp (O).
#pragma unroll
        for (int pp = 0; pp < 6; ++pp) {
            float4 vE, vO;
            if (edge) {
                int rE = refl<H>(4 * gg - 4 + 2 * pp);
                int diE = rE & 1;
                size_t off = (size_t)(rE >> 1) * WQ + jq;
                float4 p0, p1;
                c2q_quad4(pHLa[off], pHLb[off], p0, p1);
                vE = diE ? p1 : p0;  vO = diE ? p0 : p1;
            } else {
                size_t off = (size_t)(2 * gg - 2 + pp) * WQ + jq;
                c2q_quad4(pHLa[off], pHLb[off], vE, vO);
            }
            if (pp > 0) {
                int m = 2 * pp - 1;
#pragma unroll
                for (int q = 0; q < 4; ++q)
                    if (m - q >= 0 && m - q < 7) fma4(a2[q], f0[m - q], vE);
            }
            if (pp < 5) {
                int m = 2 * pp;
#pragma unroll
                for (int q = 0; q < 4; ++q)
                    if (m - q >= 0 && m - q < 7) fma4(a2[q], f0[m - q], vO);
            }
        }
        // LH (f1 into a1) and HH (f1 into a2): pairs pp -> window m = 2pp (E), 2pp+1 (O).
#pragma unroll
        for (int pp = 0; pp < 4; ++pp) {
            size_t off;
            int diE = 0;
            if (edge) {
                int rE = refl<H>(4 * gg - 2 + 2 * pp);
                diE = rE & 1;
                off = (size_t)(rE >> 1) * WQ + jq;
            } else {
                off = (size_t)(2 * gg - 1 + pp) * WQ + jq;
            }
            float4 p0, p1, vE, vO;
            c2q_quad4(pLHa[off], pLHb[off], p0, p1);
            vE = diE ? p1 : p0;  vO = diE ? p0 : p1;
            {
                int m = 2 * pp;
#pragma unroll
                for (int q = 0; q < 4; ++q)
                    if (m - q >= 0 && m - q < 5) fma4(a1[q], f1[m - q], vE);
            }
            {
                int m = 2 * pp + 1;
#pragma unroll
                for (int q = 0; q < 4; ++q)
                    if (m - q >= 0 && m - q < 5) fma4(a1[q], f1[m - q], vO);
            }
            c2q_quad4(pHHa[off], pHHb[off], p0, p1);
            vE = diE ? p1 : p0;  vO = diE ? p0 : p1;
            {
                int m = 2 * pp;
#pragma unroll
                for (int q = 0; q < 4; ++q)
                    if (m - q >= 0 && m - q < 5) fma4(a2[q], f1[m - q], vE);
            }
            {
                int m = 2 * pp + 1;
#pragma unroll
                for (int q = 0; q < 4; ++q)
                    if (m - q >= 0 && m - q < 5) fma4(a2[q], f1[m - q], vO);
            }
        }
        int rl = 4 * gl, xc2 = 2 * jq + 2;
#pragma unroll
        for (int q = 0; q < 4; ++q) {
            Y1h[rl + q][xc2]     = __float22half2_rn(make_float2(a1[q].x, a1[q].y));
            Y1h[rl + q][xc2 + 1] = __float22half2_rn(make_float2(a1[q].z, a1[q].w));
            Y2h[rl + q][xc2]     = __float22half2_rn(make_float2(a2[q].x, a2[q].y));
            Y2h[rl + q][xc2 + 1] = __float22half2_rn(make_float2(a2[q].z, a2[q].w));
        }
    }
    __syncthreads();

    // ---- Halo fill.
    for (int t = threadIdx.x; t < TY * 5; t += 256) {
        int r = t / 5, h = t % 5;
        int dst, src;
        if (h < 2) { dst = h;              src = 3 - h; }
        else       { int k = h - 2; dst = W2 + 2 + k; src = W2 + 1 - k; }
        Y1h[r][dst] = h2swap(Y1h[r][src]);
        Y2h[r][dst] = h2swap(Y2h[r][src]);
    }
    __syncthreads();

    // ---- Stage B: row filter from fp16 LDS, dense half2 reads; nt float4 store.
    constexpr int QW = W / 4;
    for (int task = threadIdx.x; task < TY * QW; task += 256) {
        int jq = task & (QW - 1);
        int r  = task / QW;
        float a[12], b[8];
#pragma unroll
        for (int m = 0; m < 6; ++m) {
            float2 u = __half22float2(Y1h[r][2 * jq + m]);
            a[2 * m] = u.x; a[2 * m + 1] = u.y;
        }
#pragma unroll
        for (int m = 0; m < 4; ++m) {
            float2 u = __half22float2(Y2h[r][2 * jq + 1 + m]);
            b[2 * m] = u.x; b[2 * m + 1] = u.y;
        }
        float acc[4] = {0.f, 0.f, 0.f, 0.f};
#pragma unroll
        for (int q = 0; q < 4; ++q) {
#pragma unroll
            for (int t = 0; t < 7; ++t) acc[q] += f0[t] * a[q + t + 1];
#pragma unroll
            for (int t = 0; t < 5; ++t) acc[q] += f1[t] * b[q + t];
        }
        nfloat4 nv = {acc[0], acc[1], acc[2], acc[3]};
        __builtin_nontemporal_store(nv,
            (nfloat4*)(out + ((size_t)nc * H + r0 + r) * W + 4 * jq));
    }
}

extern "C" void kernel_launch(void* const* d_in, const int* in_sizes, int n_in,
                              void* d_out, int out_size, void* d_ws, size_t ws_size,
                              hipStream_t stream) {
    const float* yl  = (const float*)d_in[0];
    const float* yh0 = (const float*)d_in[1];
    const float* yh1 = (const float*)d_in[2];
    const float* yh2 = (const float*)d_in[3];
    const float* g0o = (const float*)d_in[4];
    const float* g1o = (const float*)d_in[5];
    const float* g0a = (const float*)d_in[6];
    const float* g0b = (const float*)d_in[7];
    const float* g1a = (const float*)d_in[8];
    const float* g1b = (const float*)d_in[9];
    float* out = (float*)d_out;

    char* ws = (char*)d_ws;
    __half* bufA = (__half*)(ws);                       // ll 256x256 fp16: 8.4 MB
    __half* bufB = (__half*)(ws + ((size_t)64 << 20));  // ll 512x512 fp16: 33.6 MB

    // Level 2: yl fp32 + yh2 -> ll(256) fp16. TY=32, SLABS=8 -> 512 blocks.
    k_i<128, 128, 32, float, __half><<<8 * NC, 256, 0, stream>>>(
        yl, yh2, bufA, g0a, g0b, g1a, g1b);
    // Level 1: ll(256) fp16 + yh1 -> ll(512) fp16. TY=16, SLABS=32 -> 2048 blocks.
    k_i<256, 256, 16, __half, __half><<<32 * NC, 256, 0, stream>>>(
        bufA, yh1, bufB, g0a, g0b, g1a, g1b);
    // Level 0: ll(512) fp16 + yh0 -> out fp32. TY=8, SLABS=64 -> 4096 blocks.
    k_f0<512, 512, 8, __half><<<64 * NC, 256, 0, stream>>>(
        bufB, yh0, out, g0o, g1o);
}

// Round 11
// 107.161 us; speedup vs baseline: 4.0487x; 4.0487x over previous
//
#include <hip/hip_runtime.h>
#include <hip/hip_fp16.h>

#define SQH 0.70710678118654752440f
#define NC 64

typedef float nfloat4 __attribute__((ext_vector_type(4)));

// Half-sample symmetric reflection, L a compile-time power of two.
template<int L>
static __device__ __forceinline__ int refl(int i) {
    int j = i & (2 * L - 1);
    return (j >= L) ? (2 * L - 1 - j) : j;
}

// c2q on a float4 = two adjacent complex pairs (cols 2jj..2jj+3).
// p0 = values at even row (2ii), p1 = values at odd row (2ii+1).
static __device__ __forceinline__ void c2q_quad4(float4 A, float4 B,
                                                 float4& p0, float4& p1) {
    p0 = make_float4(SQH * (A.x + B.x), SQH * (A.y + B.y),
                     SQH * (A.z + B.z), SQH * (A.w + B.w));
    p1 = make_float4(SQH * (A.y - B.y), SQH * (B.x - A.x),
                     SQH * (A.w - B.w), SQH * (B.z - A.z));
}

static __device__ __forceinline__ void fma4(float4& a, float s, float4 v) {
    a.x += s * v.x; a.y += s * v.y; a.z += s * v.z; a.w += s * v.w;
}

// 4-element group load/store, fp32 or fp16 backing.
static __device__ __forceinline__ float4 ld4(const float* p, size_t i4) {
    return ((const float4*)p)[i4];
}
static __device__ __forceinline__ float4 ld4(const __half* p, size_t i4) {
    const __half2* h = (const __half2*)p;
    float2 lo = __half22float2(h[2 * i4]);
    float2 hi = __half22float2(h[2 * i4 + 1]);
    return make_float4(lo.x, lo.y, hi.x, hi.y);
}
static __device__ __forceinline__ void st4(float* p, size_t i4, float4 v) {
    ((float4*)p)[i4] = v;
}
static __device__ __forceinline__ void st4(__half* p, size_t i4, float4 v) {
    __half2* h = (__half2*)p;
    h[2 * i4]     = __float22half2_rn(make_float2(v.x, v.y));
    h[2 * i4 + 1] = __float22half2_rn(make_float2(v.z, v.w));
}

static __device__ __forceinline__ __half2 h2swap(__half2 v) {
    __half2 r; r.x = v.y; r.y = v.x; return r;
}

// ---- Fused inverse level: colifilt (c2q fused) -> fp16 LDS(+refl halo) -> rowifilt.
// ll: (NC,R_,W_), yh: (NC,6,R_/2,W_/2,2) -> out: (NC,2R_,2W_).
// Stage-A task = 4 cols x 4 output rows. Natural VGPR (no min-wave cap: R10
// showed launch_bounds(256,8) => 32-VGPR cap => 400 MB scratch spill).
template<int R_, int W_, int TY, typename InT, typename OutT>
__global__ __launch_bounds__(256) void k_i(const InT* __restrict__ ll,
                                           const float* __restrict__ yh,
                                           OutT* __restrict__ out,
                                           const float* __restrict__ g0a, const float* __restrict__ g0b,
                                           const float* __restrict__ g1a, const float* __restrict__ g1b) {
    constexpr int RH = R_ / 2, WQ = W_ / 4, W2 = W_ / 2;
    constexpr int SLABS = 2 * R_ / TY;
    constexpr int SW2 = W2 + 5;            // [2 left-halo | W2 | 3 right-halo] half2
    __shared__ __half2 Y1h[TY][SW2], Y2h[TY][SW2];

    constexpr int NBLK = SLABS * NC;
    int bid = blockIdx.x;
    int idx = (bid & 7) * (NBLK >> 3) + (bid >> 3);
    int nc = idx / SLABS, slab = idx % SLABS;
    int nc6 = nc * 6;
    int R0 = slab * TY, i0 = R0 >> 2;
    bool edge = (slab == 0) || (slab == SLABS - 1);

    const InT* llp = ll + (size_t)nc * R_ * W_;
    const float4* yh4 = (const float4*)yh;
    const float4* pHLa = yh4 + (size_t)(nc6 + 2) * RH * WQ;
    const float4* pHLb = yh4 + (size_t)(nc6 + 3) * RH * WQ;
    const float4* pLHa = yh4 + (size_t)(nc6 + 0) * RH * WQ;
    const float4* pLHb = yh4 + (size_t)(nc6 + 5) * RH * WQ;
    const float4* pHHa = yh4 + (size_t)(nc6 + 1) * RH * WQ;
    const float4* pHHb = yh4 + (size_t)(nc6 + 4) * RH * WQ;

    // ---- Stage A: column inverse filter. Task = 4 cols x 4 output rows.
    constexpr int ATASK = WQ * (TY / 4);
    for (int task = threadIdx.x; task < ATASK; task += 256) {
        int jq = task & (WQ - 1);
        int gl = task / WQ;
        int i  = i0 + gl;

        float4 a10 = {0,0,0,0}, a20 = {0,0,0,0}, a11 = {0,0,0,0}, a21 = {0,0,0,0};
        float4 a12 = {0,0,0,0}, a22 = {0,0,0,0}, a13 = {0,0,0,0}, a23 = {0,0,0,0};
#pragma unroll
        for (int t = 0; t < 5; ++t) {
            float4 lE, lO, hlE, hlO, lhE, lhO, hhE, hhO;
            if (edge) {
                int rE = refl<R_>(2 * i - 4 + 2 * t);
                int rO = refl<R_>(2 * i - 3 + 2 * t);
                lE = ld4(llp, (size_t)rE * WQ + jq);
                lO = ld4(llp, (size_t)rO * WQ + jq);
                int diE = rE & 1;
                size_t off = (size_t)(rE >> 1) * WQ + jq;
                float4 p0, p1;
                c2q_quad4(pHLa[off], pHLb[off], p0, p1);
                hlE = diE ? p1 : p0;  hlO = diE ? p0 : p1;
                c2q_quad4(pLHa[off], pLHb[off], p0, p1);
                lhE = diE ? p1 : p0;  lhO = diE ? p0 : p1;
                c2q_quad4(pHHa[off], pHHb[off], p0, p1);
                hhE = diE ? p1 : p0;  hhO = diE ? p0 : p1;
            } else {
                lE = ld4(llp, (size_t)(2 * i - 4 + 2 * t) * WQ + jq);
                lO = ld4(llp, (size_t)(2 * i - 3 + 2 * t) * WQ + jq);
                size_t off = (size_t)(i - 2 + t) * WQ + jq;
                c2q_quad4(pHLa[off], pHLb[off], hlE, hlO);
                c2q_quad4(pLHa[off], pLHb[off], lhE, lhO);
                c2q_quad4(pHHa[off], pHHb[off], hhE, hhO);
            }
            float b0o = g0b[2 * t + 1], a0o = g0a[2 * t + 1];
            float b0e = g0b[2 * t],     a0e = g0a[2 * t];
            float b1o = g1b[2 * t + 1], a1o = g1a[2 * t + 1];
            float b1e = g1b[2 * t],     a1e = g1a[2 * t];
            fma4(a10, b0o, lE);  fma4(a10, b1o, lhO);
            fma4(a20, b0o, hlE); fma4(a20, b1o, hhO);
            fma4(a11, a0o, lO);  fma4(a11, a1o, lhE);
            fma4(a21, a0o, hlO); fma4(a21, a1o, hhE);
            fma4(a12, b0e, lE);  fma4(a12, b1e, lhO);
            fma4(a22, b0e, hlE); fma4(a22, b1e, hhO);
            fma4(a13, a0e, lO);  fma4(a13, a1e, lhE);
            fma4(a23, a0e, hlO); fma4(a23, a1e, hhE);
        }
        int rl = 4 * gl, xc2 = 2 * jq + 2;
        Y1h[rl + 0][xc2] = __float22half2_rn(make_float2(a10.x, a10.y));
        Y1h[rl + 0][xc2 + 1] = __float22half2_rn(make_float2(a10.z, a10.w));
        Y2h[rl + 0][xc2] = __float22half2_rn(make_float2(a20.x, a20.y));
        Y2h[rl + 0][xc2 + 1] = __float22half2_rn(make_float2(a20.z, a20.w));
        Y1h[rl + 1][xc2] = __float22half2_rn(make_float2(a11.x, a11.y));
        Y1h[rl + 1][xc2 + 1] = __float22half2_rn(make_float2(a11.z, a11.w));
        Y2h[rl + 1][xc2] = __float22half2_rn(make_float2(a21.x, a21.y));
        Y2h[rl + 1][xc2 + 1] = __float22half2_rn(make_float2(a21.z, a21.w));
        Y1h[rl + 2][xc2] = __float22half2_rn(make_float2(a12.x, a12.y));
        Y1h[rl + 2][xc2 + 1] = __float22half2_rn(make_float2(a12.z, a12.w));
        Y2h[rl + 2][xc2] = __float22half2_rn(make_float2(a22.x, a22.y));
        Y2h[rl + 2][xc2 + 1] = __float22half2_rn(make_float2(a22.z, a22.w));
        Y1h[rl + 3][xc2] = __float22half2_rn(make_float2(a13.x, a13.y));
        Y1h[rl + 3][xc2 + 1] = __float22half2_rn(make_float2(a13.z, a13.w));
        Y2h[rl + 3][xc2] = __float22half2_rn(make_float2(a23.x, a23.y));
        Y2h[rl + 3][xc2 + 1] = __float22half2_rn(make_float2(a23.z, a23.w));
    }
    __syncthreads();

    // ---- Halo fill: pre-reflected, pair-swapped mirrors.
    for (int t = threadIdx.x; t < TY * 5; t += 256) {
        int r = t / 5, h = t % 5;
        int dst, src;
        if (h < 2) { dst = h;              src = 3 - h; }
        else       { int k = h - 2; dst = W2 + 2 + k; src = W2 + 1 - k; }
        Y1h[r][dst] = h2swap(Y1h[r][src]);
        Y2h[r][dst] = h2swap(Y2h[r][src]);
    }
    __syncthreads();

    // ---- Stage B: row inverse filter from fp16 LDS (dense half2 reads).
    constexpr int QW = W_ / 2;   // quads per output row (2W_/4)
    for (int task = threadIdx.x; task < TY * QW; task += 256) {
        int j = task & (QW - 1);
        int r = task / QW;
        float2 v1[5], v2[5];     // .x = even series, .y = odd series
#pragma unroll
        for (int t = 0; t < 5; ++t) {
            v1[t] = __half22float2(Y1h[r][j + t]);
            v2[t] = __half22float2(Y2h[r][j + t]);
        }
        float4 o = make_float4(0.f, 0.f, 0.f, 0.f);
#pragma unroll
        for (int t = 0; t < 5; ++t) {
            float b0o = g0b[2 * t + 1], a0o = g0a[2 * t + 1];
            float b0e = g0b[2 * t],     a0e = g0a[2 * t];
            float b1o = g1b[2 * t + 1], a1o = g1a[2 * t + 1];
            float b1e = g1b[2 * t],     a1e = g1a[2 * t];
            o.x += b0o * v1[t].x + b1o * v2[t].y;
            o.y += a0o * v1[t].y + a1o * v2[t].x;
            o.z += b0e * v1[t].x + b1e * v2[t].y;
            o.w += a0e * v1[t].y + a1e * v2[t].x;
        }
        st4(out, (size_t)(nc * 2 * R_ + R0 + r) * QW + j, o);
    }
}

// ---- Fused final level: colfilter(7/5-tap, c2q fused) -> fp16 LDS -> rowfilter.
// Stage-A task = 4 cols x 4 output rows (one gg).
template<int H, int W, int TY, typename InT>
__global__ __launch_bounds__(256) void k_f0(const InT* __restrict__ ll,
                                            const float* __restrict__ yh,
                                            float* __restrict__ out,
                                            const float* __restrict__ g0o,
                                            const float* __restrict__ g1o) {
    constexpr int RH = H / 2, WQ = W / 4, W2 = W / 2;
    constexpr int SLABS = H / TY;
    constexpr int SW2 = W2 + 5;
    __shared__ __half2 Y1h[TY][SW2], Y2h[TY][SW2];

    constexpr int NBLK = SLABS * NC;
    int bid = blockIdx.x;
    int idx = (bid & 7) * (NBLK >> 3) + (bid >> 3);
    int nc = idx / SLABS, slab = idx % SLABS;
    int nc6 = nc * 6;
    int r0 = slab * TY;
    bool edge = (slab == 0) || (slab == SLABS - 1);

    const InT* llp = ll + (size_t)nc * H * W;
    const float4* yh4 = (const float4*)yh;
    const float4* pHLa = yh4 + (size_t)(nc6 + 2) * RH * WQ;
    const float4* pHLb = yh4 + (size_t)(nc6 + 3) * RH * WQ;
    const float4* pLHa = yh4 + (size_t)(nc6 + 0) * RH * WQ;
    const float4* pLHb = yh4 + (size_t)(nc6 + 5) * RH * WQ;
    const float4* pHHa = yh4 + (size_t)(nc6 + 1) * RH * WQ;
    const float4* pHHb = yh4 + (size_t)(nc6 + 4) * RH * WQ;

    float f0[7], f1[5];
#pragma unroll
    for (int k = 0; k < 7; ++k) f0[k] = g0o[k];
#pragma unroll
    for (int k = 0; k < 5; ++k) f1[k] = g1o[k];

    // ---- Stage A: column filter. Task = 4 cols x 4 output rows.
    constexpr int ATASK = WQ * (TY / 4);
    for (int task = threadIdx.x; task < ATASK; task += 256) {
        int jq = task & (WQ - 1);
        int gl = task / WQ;
        int gg = (r0 >> 2) + gl;

        float4 a1[4], a2[4];
#pragma unroll
        for (int q = 0; q < 4; ++q) { a1[q] = make_float4(0,0,0,0); a2[q] = make_float4(0,0,0,0); }

        // Lowpass path from ll: window rows 4gg-3+m, m=0..9, 7-tap f0.
#pragma unroll
        for (int m = 0; m < 10; ++m) {
            float4 v;
            if (edge) v = ld4(llp, (size_t)refl<H>(4 * gg - 3 + m) * WQ + jq);
            else      v = ld4(llp, (size_t)(4 * gg - 3 + m) * WQ + jq);
#pragma unroll
            for (int q = 0; q < 4; ++q)
                if (m - q >= 0 && m - q < 7) fma4(a1[q], f0[m - q], v);
        }
        // HL band (7-tap f0 into a2): pairs pp cover window m = 2pp-1 (E), 2pp (O).
#pragma unroll
        for (int pp = 0; pp < 6; ++pp) {
            float4 vE, vO;
            if (edge) {
                int rE = refl<H>(4 * gg - 4 + 2 * pp);
                int diE = rE & 1;
                size_t off = (size_t)(rE >> 1) * WQ + jq;
                float4 p0, p1;
                c2q_quad4(pHLa[off], pHLb[off], p0, p1);
                vE = diE ? p1 : p0;  vO = diE ? p0 : p1;
            } else {
                size_t off = (size_t)(2 * gg - 2 + pp) * WQ + jq;
                c2q_quad4(pHLa[off], pHLb[off], vE, vO);
            }
            if (pp > 0) {
                int m = 2 * pp - 1;
#pragma unroll
                for (int q = 0; q < 4; ++q)
                    if (m - q >= 0 && m - q < 7) fma4(a2[q], f0[m - q], vE);
            }
            if (pp < 5) {
                int m = 2 * pp;
#pragma unroll
                for (int q = 0; q < 4; ++q)
                    if (m - q >= 0 && m - q < 7) fma4(a2[q], f0[m - q], vO);
            }
        }
        // LH (f1 into a1) and HH (f1 into a2): pairs pp -> window m = 2pp (E), 2pp+1 (O).
#pragma unroll
        for (int pp = 0; pp < 4; ++pp) {
            size_t off;
            int diE = 0;
            if (edge) {
                int rE = refl<H>(4 * gg - 2 + 2 * pp);
                diE = rE & 1;
                off = (size_t)(rE >> 1) * WQ + jq;
            } else {
                off = (size_t)(2 * gg - 1 + pp) * WQ + jq;
            }
            float4 p0, p1, vE, vO;
            c2q_quad4(pLHa[off], pLHb[off], p0, p1);
            vE = diE ? p1 : p0;  vO = diE ? p0 : p1;
            {
                int m = 2 * pp;
#pragma unroll
                for (int q = 0; q < 4; ++q)
                    if (m - q >= 0 && m - q < 5) fma4(a1[q], f1[m - q], vE);
            }
            {
                int m = 2 * pp + 1;
#pragma unroll
                for (int q = 0; q < 4; ++q)
                    if (m - q >= 0 && m - q < 5) fma4(a1[q], f1[m - q], vO);
            }
            c2q_quad4(pHHa[off], pHHb[off], p0, p1);
            vE = diE ? p1 : p0;  vO = diE ? p0 : p1;
            {
                int m = 2 * pp;
#pragma unroll
                for (int q = 0; q < 4; ++q)
                    if (m - q >= 0 && m - q < 5) fma4(a2[q], f1[m - q], vE);
            }
            {
                int m = 2 * pp + 1;
#pragma unroll
                for (int q = 0; q < 4; ++q)
                    if (m - q >= 0 && m - q < 5) fma4(a2[q], f1[m - q], vO);
            }
        }
        int rl = 4 * gl, xc2 = 2 * jq + 2;
#pragma unroll
        for (int q = 0; q < 4; ++q) {
            Y1h[rl + q][xc2]     = __float22half2_rn(make_float2(a1[q].x, a1[q].y));
            Y1h[rl + q][xc2 + 1] = __float22half2_rn(make_float2(a1[q].z, a1[q].w));
            Y2h[rl + q][xc2]     = __float22half2_rn(make_float2(a2[q].x, a2[q].y));
            Y2h[rl + q][xc2 + 1] = __float22half2_rn(make_float2(a2[q].z, a2[q].w));
        }
    }
    __syncthreads();

    // ---- Halo fill.
    for (int t = threadIdx.x; t < TY * 5; t += 256) {
        int r = t / 5, h = t % 5;
        int dst, src;
        if (h < 2) { dst = h;              src = 3 - h; }
        else       { int k = h - 2; dst = W2 + 2 + k; src = W2 + 1 - k; }
        Y1h[r][dst] = h2swap(Y1h[r][src]);
        Y2h[r][dst] = h2swap(Y2h[r][src]);
    }
    __syncthreads();

    // ---- Stage B: row filter from fp16 LDS, dense half2 reads; nt float4 store.
    constexpr int QW = W / 4;
    for (int task = threadIdx.x; task < TY * QW; task += 256) {
        int jq = task & (QW - 1);
        int r  = task / QW;
        float a[12], b[8];
#pragma unroll
        for (int m = 0; m < 6; ++m) {
            float2 u = __half22float2(Y1h[r][2 * jq + m]);
            a[2 * m] = u.x; a[2 * m + 1] = u.y;
        }
#pragma unroll
        for (int m = 0; m < 4; ++m) {
            float2 u = __half22float2(Y2h[r][2 * jq + 1 + m]);
            b[2 * m] = u.x; b[2 * m + 1] = u.y;
        }
        float acc[4] = {0.f, 0.f, 0.f, 0.f};
#pragma unroll
        for (int q = 0; q < 4; ++q) {
#pragma unroll
            for (int t = 0; t < 7; ++t) acc[q] += f0[t] * a[q + t + 1];
#pragma unroll
            for (int t = 0; t < 5; ++t) acc[q] += f1[t] * b[q + t];
        }
        nfloat4 nv = {acc[0], acc[1], acc[2], acc[3]};
        __builtin_nontemporal_store(nv,
            (nfloat4*)(out + ((size_t)nc * H + r0 + r) * W + 4 * jq));
    }
}

extern "C" void kernel_launch(void* const* d_in, const int* in_sizes, int n_in,
                              void* d_out, int out_size, void* d_ws, size_t ws_size,
                              hipStream_t stream) {
    const float* yl  = (const float*)d_in[0];
    const float* yh0 = (const float*)d_in[1];
    const float* yh1 = (const float*)d_in[2];
    const float* yh2 = (const float*)d_in[3];
    const float* g0o = (const float*)d_in[4];
    const float* g1o = (const float*)d_in[5];
    const float* g0a = (const float*)d_in[6];
    const float* g0b = (const float*)d_in[7];
    const float* g1a = (const float*)d_in[8];
    const float* g1b = (const float*)d_in[9];
    float* out = (float*)d_out;

    char* ws = (char*)d_ws;
    __half* bufA = (__half*)(ws);                       // ll 256x256 fp16: 8.4 MB
    __half* bufB = (__half*)(ws + ((size_t)64 << 20));  // ll 512x512 fp16: 33.6 MB

    // Level 2: yl fp32 + yh2 -> ll(256) fp16. TY=32, SLABS=8 -> 512 blocks.
    k_i<128, 128, 32, float, __half><<<8 * NC, 256, 0, stream>>>(
        yl, yh2, bufA, g0a, g0b, g1a, g1b);
    // Level 1: ll(256) fp16 + yh1 -> ll(512) fp16. TY=16, SLABS=32 -> 2048 blocks.
    k_i<256, 256, 16, __half, __half><<<32 * NC, 256, 0, stream>>>(
        bufA, yh1, bufB, g0a, g0b, g1a, g1b);
    // Level 0: ll(512) fp16 + yh0 -> out fp32. TY=8, SLABS=64 -> 4096 blocks.
    k_f0<512, 512, 8, __half><<<64 * NC, 256, 0, stream>>>(
        bufB, yh0, out, g0o, g1o);
}

// Round 12
// 104.890 us; speedup vs baseline: 4.1364x; 1.0217x over previous
//
#include <hip/hip_runtime.h>
#include <hip/hip_fp16.h>

#define SQH 0.70710678118654752440f
#define NC 64

typedef float nfloat4 __attribute__((ext_vector_type(4)));

// Half-sample symmetric reflection, L a compile-time power of two.
template<int L>
static __device__ __forceinline__ int refl(int i) {
    int j = i & (2 * L - 1);
    return (j >= L) ? (2 * L - 1 - j) : j;
}

// c2q on a float4 = two adjacent complex pairs (cols 2jj..2jj+3).
// p0 = values at even row (2ii), p1 = values at odd row (2ii+1).
static __device__ __forceinline__ void c2q_quad4(float4 A, float4 B,
                                                 float4& p0, float4& p1) {
    p0 = make_float4(SQH * (A.x + B.x), SQH * (A.y + B.y),
                     SQH * (A.z + B.z), SQH * (A.w + B.w));
    p1 = make_float4(SQH * (A.y - B.y), SQH * (B.x - A.x),
                     SQH * (A.w - B.w), SQH * (B.z - A.z));
}

static __device__ __forceinline__ void fma4(float4& a, float s, float4 v) {
    a.x += s * v.x; a.y += s * v.y; a.z += s * v.z; a.w += s * v.w;
}

// 4-element group load/store, fp32 or fp16 backing.
static __device__ __forceinline__ float4 ld4(const float* p, size_t i4) {
    return ((const float4*)p)[i4];
}
static __device__ __forceinline__ float4 ld4(const __half* p, size_t i4) {
    const __half2* h = (const __half2*)p;
    float2 lo = __half22float2(h[2 * i4]);
    float2 hi = __half22float2(h[2 * i4 + 1]);
    return make_float4(lo.x, lo.y, hi.x, hi.y);
}
static __device__ __forceinline__ void st4(float* p, size_t i4, float4 v) {
    ((float4*)p)[i4] = v;
}
static __device__ __forceinline__ void st4(__half* p, size_t i4, float4 v) {
    __half2* h = (__half2*)p;
    h[2 * i4]     = __float22half2_rn(make_float2(v.x, v.y));
    h[2 * i4 + 1] = __float22half2_rn(make_float2(v.z, v.w));
}

// ---- Fused inverse level: colifilt (c2q fused, both branches) -> LDS(+refl halo) -> rowifilt.
// ll: (NC,R_,W_), yh: (NC,6,R_/2,W_/2,2) -> out: (NC,2R_,2W_).
// Stage-A task = 4 cols x 4 rows, loads fused with accumulation.
template<int R_, int W_, int TY, typename InT, typename OutT>
__global__ __launch_bounds__(256) void k_i(const InT* __restrict__ ll,
                                           const float* __restrict__ yh,
                                           OutT* __restrict__ out,
                                           const float* __restrict__ g0a, const float* __restrict__ g0b,
                                           const float* __restrict__ g1a, const float* __restrict__ g1b) {
    constexpr int RH = R_ / 2, WQ = W_ / 4;
    constexpr int SLABS = 2 * R_ / TY;
    constexpr int SW = W_ + 12;
    __shared__ float Y1[TY][SW], Y2[TY][SW];

    constexpr int NBLK = SLABS * NC;
    int bid = blockIdx.x;
    int idx = (bid & 7) * (NBLK >> 3) + (bid >> 3);
    int nc = idx / SLABS, slab = idx % SLABS;
    int nc6 = nc * 6;
    int R0 = slab * TY, i0 = R0 >> 2;
    bool edge = (slab == 0) || (slab == SLABS - 1);

    const InT* llp = ll + (size_t)nc * R_ * W_;
    const float4* yh4 = (const float4*)yh;
    const float4* pHLa = yh4 + (size_t)(nc6 + 2) * RH * WQ;
    const float4* pHLb = yh4 + (size_t)(nc6 + 3) * RH * WQ;
    const float4* pLHa = yh4 + (size_t)(nc6 + 0) * RH * WQ;
    const float4* pLHb = yh4 + (size_t)(nc6 + 5) * RH * WQ;
    const float4* pHHa = yh4 + (size_t)(nc6 + 1) * RH * WQ;
    const float4* pHHb = yh4 + (size_t)(nc6 + 4) * RH * WQ;

    // ---- Stage A: column inverse filter. Task = 4 cols x 4 output rows.
    constexpr int ATASK = WQ * (TY / 4);
    for (int task = threadIdx.x; task < ATASK; task += 256) {
        int jq = task & (WQ - 1);
        int gl = task / WQ;
        int i  = i0 + gl;

        float4 a10 = {0,0,0,0}, a20 = {0,0,0,0}, a11 = {0,0,0,0}, a21 = {0,0,0,0};
        float4 a12 = {0,0,0,0}, a22 = {0,0,0,0}, a13 = {0,0,0,0}, a23 = {0,0,0,0};
#pragma unroll
        for (int t = 0; t < 5; ++t) {
            float4 lE, lO, hlE, hlO, lhE, lhO, hhE, hhO;
            if (edge) {
                int rE = refl<R_>(2 * i - 4 + 2 * t);
                int rO = refl<R_>(2 * i - 3 + 2 * t);
                lE = ld4(llp, (size_t)rE * WQ + jq);
                lO = ld4(llp, (size_t)rO * WQ + jq);
                int diE = rE & 1;
                size_t off = (size_t)(rE >> 1) * WQ + jq;
                float4 p0, p1;
                c2q_quad4(pHLa[off], pHLb[off], p0, p1);
                hlE = diE ? p1 : p0;  hlO = diE ? p0 : p1;
                c2q_quad4(pLHa[off], pLHb[off], p0, p1);
                lhE = diE ? p1 : p0;  lhO = diE ? p0 : p1;
                c2q_quad4(pHHa[off], pHHb[off], p0, p1);
                hhE = diE ? p1 : p0;  hhO = diE ? p0 : p1;
            } else {
                lE = ld4(llp, (size_t)(2 * i - 4 + 2 * t) * WQ + jq);
                lO = ld4(llp, (size_t)(2 * i - 3 + 2 * t) * WQ + jq);
                size_t off = (size_t)(i - 2 + t) * WQ + jq;
                c2q_quad4(pHLa[off], pHLb[off], hlE, hlO);
                c2q_quad4(pLHa[off], pLHb[off], lhE, lhO);
                c2q_quad4(pHHa[off], pHHb[off], hhE, hhO);
            }
            float b0o = g0b[2 * t + 1], a0o = g0a[2 * t + 1];
            float b0e = g0b[2 * t],     a0e = g0a[2 * t];
            float b1o = g1b[2 * t + 1], a1o = g1a[2 * t + 1];
            float b1e = g1b[2 * t],     a1e = g1a[2 * t];
            fma4(a10, b0o, lE);  fma4(a10, b1o, lhO);
            fma4(a20, b0o, hlE); fma4(a20, b1o, hhO);
            fma4(a11, a0o, lO);  fma4(a11, a1o, lhE);
            fma4(a21, a0o, hlO); fma4(a21, a1o, hhE);
            fma4(a12, b0e, lE);  fma4(a12, b1e, lhO);
            fma4(a22, b0e, hlE); fma4(a22, b1e, hhO);
            fma4(a13, a0e, lO);  fma4(a13, a1e, lhE);
            fma4(a23, a0e, hlO); fma4(a23, a1e, hhE);
        }
        int rl = 4 * gl, xc = 4 * jq + 4;
        *(float4*)&Y1[rl + 0][xc] = a10;  *(float4*)&Y2[rl + 0][xc] = a20;
        *(float4*)&Y1[rl + 1][xc] = a11;  *(float4*)&Y2[rl + 1][xc] = a21;
        *(float4*)&Y1[rl + 2][xc] = a12;  *(float4*)&Y2[rl + 2][xc] = a22;
        *(float4*)&Y1[rl + 3][xc] = a13;  *(float4*)&Y2[rl + 3][xc] = a23;
    }
    __syncthreads();

    // ---- Halo fill (pre-reflected cols): raw -k -> k-1 ; raw W_+k -> W_-1-k.
    for (int t = threadIdx.x; t < TY * 9; t += 256) {
        int r = t / 9, h = t % 9;
        int dst, src;
        if (h < 4) { dst = h;              src = 7 - h; }
        else       { int k = h - 4; dst = 4 + W_ + k; src = 4 + W_ - 1 - k; }
        Y1[r][dst] = Y1[r][src];
        Y2[r][dst] = Y2[r][src];
    }
    __syncthreads();

    // ---- Stage B: row inverse filter from LDS (no refl, aligned float2 reads).
    constexpr int QW = W_ / 2;   // quads per output row
    for (int task = threadIdx.x; task < TY * QW; task += 256) {
        int j = task & (QW - 1);
        int r = task / QW;
        float2 v1[5], v2[5];     // .x = even series, .y = odd series
#pragma unroll
        for (int t = 0; t < 5; ++t) {
            v1[t] = *(const float2*)&Y1[r][2 * j + 2 * t];
            v2[t] = *(const float2*)&Y2[r][2 * j + 2 * t];
        }
        float4 o = make_float4(0.f, 0.f, 0.f, 0.f);
#pragma unroll
        for (int t = 0; t < 5; ++t) {
            float b0o = g0b[2 * t + 1], a0o = g0a[2 * t + 1];
            float b0e = g0b[2 * t],     a0e = g0a[2 * t];
            float b1o = g1b[2 * t + 1], a1o = g1a[2 * t + 1];
            float b1e = g1b[2 * t],     a1e = g1a[2 * t];
            o.x += b0o * v1[t].x + b1o * v2[t].y;
            o.y += a0o * v1[t].y + a1o * v2[t].x;
            o.z += b0e * v1[t].x + b1e * v2[t].y;
            o.w += a0e * v1[t].y + a1e * v2[t].x;
        }
        st4(out, (size_t)(nc * 2 * R_ + R0 + r) * QW + j, o);
    }
}

// ---- Fused final level: colfilter(7/5-tap, c2q fused) -> LDS(+refl halo) -> rowfilter.
// ll: (NC,H,W) fp16, yh: (NC,6,H/2,W/2,2) -> out: (NC,H,W) fp32 nt-store.
template<int H, int W, int TY, typename InT>
__global__ __launch_bounds__(256) void k_f0(const InT* __restrict__ ll,
                                            const float* __restrict__ yh,
                                            float* __restrict__ out,
                                            const float* __restrict__ g0o,
                                            const float* __restrict__ g1o) {
    constexpr int RH = H / 2, WQ = W / 4;
    constexpr int SLABS = H / TY;
    constexpr int SW = W + 12;
    __shared__ float Y1[TY][SW], Y2[TY][SW];

    constexpr int NBLK = SLABS * NC;
    int bid = blockIdx.x;
    int idx = (bid & 7) * (NBLK >> 3) + (bid >> 3);
    int nc = idx / SLABS, slab = idx % SLABS;
    int nc6 = nc * 6;
    int r0 = slab * TY;
    bool edge = (slab == 0) || (slab == SLABS - 1);

    const InT* llp = ll + (size_t)nc * H * W;
    const float4* yh4 = (const float4*)yh;
    const float4* pHLa = yh4 + (size_t)(nc6 + 2) * RH * WQ;
    const float4* pHLb = yh4 + (size_t)(nc6 + 3) * RH * WQ;
    const float4* pLHa = yh4 + (size_t)(nc6 + 0) * RH * WQ;
    const float4* pLHb = yh4 + (size_t)(nc6 + 5) * RH * WQ;
    const float4* pHHa = yh4 + (size_t)(nc6 + 1) * RH * WQ;
    const float4* pHHb = yh4 + (size_t)(nc6 + 4) * RH * WQ;

    float f0[7], f1[5];
#pragma unroll
    for (int k = 0; k < 7; ++k) f0[k] = g0o[k];
#pragma unroll
    for (int k = 0; k < 5; ++k) f1[k] = g1o[k];

    // ---- Stage A: column filter. Task = 4 cols x 4 output rows, fused loads+fma.
    constexpr int ATASK = WQ * (TY / 4);
    for (int task = threadIdx.x; task < ATASK; task += 256) {
        int jq = task & (WQ - 1);
        int gl = task / WQ;
        int gg = (r0 >> 2) + gl;

        float4 a1[4], a2[4];
#pragma unroll
        for (int q = 0; q < 4; ++q) { a1[q] = make_float4(0,0,0,0); a2[q] = make_float4(0,0,0,0); }

        // Lowpass path from ll: window rows 4gg-3+m, m=0..9, 7-tap f0.
#pragma unroll
        for (int m = 0; m < 10; ++m) {
            float4 v;
            if (edge) v = ld4(llp, (size_t)refl<H>(4 * gg - 3 + m) * WQ + jq);
            else      v = ld4(llp, (size_t)(4 * gg - 3 + m) * WQ + jq);
#pragma unroll
            for (int q = 0; q < 4; ++q)
                if (m - q >= 0 && m - q < 7) fma4(a1[q], f0[m - q], v);
        }
        // HL band (7-tap f0 into a2): pairs pp cover window m = 2pp-1 (E), 2pp (O).
#pragma unroll
        for (int pp = 0; pp < 6; ++pp) {
            float4 vE, vO;
            if (edge) {
                int rE = refl<H>(4 * gg - 4 + 2 * pp);
                int diE = rE & 1;
                size_t off = (size_t)(rE >> 1) * WQ + jq;
                float4 p0, p1;
                c2q_quad4(pHLa[off], pHLb[off], p0, p1);
                vE = diE ? p1 : p0;  vO = diE ? p0 : p1;
            } else {
                size_t off = (size_t)(2 * gg - 2 + pp) * WQ + jq;
                c2q_quad4(pHLa[off], pHLb[off], vE, vO);
            }
            if (pp > 0) {
                int m = 2 * pp - 1;
#pragma unroll
                for (int q = 0; q < 4; ++q)
                    if (m - q >= 0 && m - q < 7) fma4(a2[q], f0[m - q], vE);
            }
            if (pp < 5) {
                int m = 2 * pp;
#pragma unroll
                for (int q = 0; q < 4; ++q)
                    if (m - q >= 0 && m - q < 7) fma4(a2[q], f0[m - q], vO);
            }
        }
        // LH (f1 into a1) and HH (f1 into a2): pairs pp -> window m = 2pp (E), 2pp+1 (O).
#pragma unroll
        for (int pp = 0; pp < 4; ++pp) {
            size_t off;
            int diE = 0;
            if (edge) {
                int rE = refl<H>(4 * gg - 2 + 2 * pp);
                diE = rE & 1;
                off = (size_t)(rE >> 1) * WQ + jq;
            } else {
                off = (size_t)(2 * gg - 1 + pp) * WQ + jq;
            }
            float4 p0, p1, vE, vO;
            c2q_quad4(pLHa[off], pLHb[off], p0, p1);
            vE = diE ? p1 : p0;  vO = diE ? p0 : p1;
            {
                int m = 2 * pp;
#pragma unroll
                for (int q = 0; q < 4; ++q)
                    if (m - q >= 0 && m - q < 5) fma4(a1[q], f1[m - q], vE);
            }
            {
                int m = 2 * pp + 1;
#pragma unroll
                for (int q = 0; q < 4; ++q)
                    if (m - q >= 0 && m - q < 5) fma4(a1[q], f1[m - q], vO);
            }
            c2q_quad4(pHHa[off], pHHb[off], p0, p1);
            vE = diE ? p1 : p0;  vO = diE ? p0 : p1;
            {
                int m = 2 * pp;
#pragma unroll
                for (int q = 0; q < 4; ++q)
                    if (m - q >= 0 && m - q < 5) fma4(a2[q], f1[m - q], vE);
            }
            {
                int m = 2 * pp + 1;
#pragma unroll
                for (int q = 0; q < 4; ++q)
                    if (m - q >= 0 && m - q < 5) fma4(a2[q], f1[m - q], vO);
            }
        }
        int rl = 4 * gl, xc = 4 * jq + 4;
#pragma unroll
        for (int q = 0; q < 4; ++q) {
            *(float4*)&Y1[rl + q][xc] = a1[q];
            *(float4*)&Y2[rl + q][xc] = a2[q];
        }
    }
    __syncthreads();

    // ---- Halo fill.
    for (int t = threadIdx.x; t < TY * 9; t += 256) {
        int r = t / 9, h = t % 9;
        int dst, src;
        if (h < 4) { dst = h;              src = 7 - h; }
        else       { int k = h - 4; dst = 4 + W + k; src = 4 + W - 1 - k; }
        Y1[r][dst] = Y1[r][src];
        Y2[r][dst] = Y2[r][src];
    }
    __syncthreads();

    // ---- Stage B: row filter from LDS, no refl, aligned float2 reads; nt float4 store.
    constexpr int QW = W / 4;
    for (int task = threadIdx.x; task < TY * QW; task += 256) {
        int jq = task & (QW - 1);
        int r  = task / QW;
        int c0 = 4 * jq;           // LDS idx c0+k holds raw col c0-4+k
        float a[12], b[8];
#pragma unroll
        for (int m = 0; m < 6; ++m) {
            float2 u = *(const float2*)&Y1[r][c0 + 2 * m];
            a[2 * m] = u.x; a[2 * m + 1] = u.y;
        }
#pragma unroll
        for (int m = 0; m < 4; ++m) {
            float2 u = *(const float2*)&Y2[r][c0 + 2 + 2 * m];
            b[2 * m] = u.x; b[2 * m + 1] = u.y;
        }
        float acc[4] = {0.f, 0.f, 0.f, 0.f};
#pragma unroll
        for (int q = 0; q < 4; ++q) {
#pragma unroll
            for (int t = 0; t < 7; ++t) acc[q] += f0[t] * a[q + t + 1];
#pragma unroll
            for (int t = 0; t < 5; ++t) acc[q] += f1[t] * b[q + t];
        }
        nfloat4 nv = {acc[0], acc[1], acc[2], acc[3]};
        __builtin_nontemporal_store(nv,
            (nfloat4*)(out + ((size_t)nc * H + r0 + r) * W + c0));
    }
}

extern "C" void kernel_launch(void* const* d_in, const int* in_sizes, int n_in,
                              void* d_out, int out_size, void* d_ws, size_t ws_size,
                              hipStream_t stream) {
    const float* yl  = (const float*)d_in[0];
    const float* yh0 = (const float*)d_in[1];
    const float* yh1 = (const float*)d_in[2];
    const float* yh2 = (const float*)d_in[3];
    const float* g0o = (const float*)d_in[4];
    const float* g1o = (const float*)d_in[5];
    const float* g0a = (const float*)d_in[6];
    const float* g0b = (const float*)d_in[7];
    const float* g1a = (const float*)d_in[8];
    const float* g1b = (const float*)d_in[9];
    float* out = (float*)d_out;

    char* ws = (char*)d_ws;
    __half* bufA = (__half*)(ws);                       // ll 256x256 fp16: 8.4 MB
    __half* bufB = (__half*)(ws + ((size_t)64 << 20));  // ll 512x512 fp16: 33.6 MB

    // Level 2: yl fp32 + yh2 -> ll(256) fp16. SLABS=8 -> 512 blocks.
    k_i<128, 128, 32, float, __half><<<8 * NC, 256, 0, stream>>>(
        yl, yh2, bufA, g0a, g0b, g1a, g1b);
    // Level 1: ll(256) fp16 + yh1 -> ll(512) fp16. SLABS=32 -> 2048 blocks.
    k_i<256, 256, 16, __half, __half><<<32 * NC, 256, 0, stream>>>(
        bufA, yh1, bufB, g0a, g0b, g1a, g1b);
    // Level 0: ll(512) fp16 + yh0 -> out fp32. SLABS=64 -> 4096 blocks.
    k_f0<512, 512, 8, __half><<<64 * NC, 256, 0, stream>>>(
        bufB, yh0, out, g0o, g1o);
}